// Round 3
// baseline (164.338 us; speedup 1.0000x reference)
//
#include <hip/hip_runtime.h>

#define NB    256
#define UNITS 1024
#define EDIM  1024
#define MEM   128
#define LDA   2048   // inputs row stride (EDIM + UNITS)

// d_out layout (floats): output[256*1024] | new_M_key[256*128*1024] | new_M_value[256*128*1024]
#define KEY_OFF ((size_t)NB * UNITS)
#define VAL_OFF (KEY_OFF + (size_t)NB * MEM * UNITS)

typedef float nfloat4 __attribute__((ext_vector_type(4)));

__device__ __forceinline__ void nt_store4(float* p, float4 v) {
    nfloat4 nv = {v.x, v.y, v.z, v.w};
    __builtin_nontemporal_store(nv, (nfloat4*)p);
}

// One kernel, 256 blocks x 1024 threads. Waves 0-7: fused softmax-attention +
// memory shift (HBM-streaming). Waves 8-15: the two 256x1024x1024 fp32 GEMMs
// (row 127 of new_M_key/new_M_value), register-tiled 32x32 per wave, split-K=4,
// operands read through L2/L3 (A=2MB, W=8MB cache-resident), partials reduced
// in LDS. Both paths execute exactly 4 __syncthreads -> no barrier divergence.
__global__ __launch_bounds__(1024, 4) void k_all(
    const float* __restrict__ inputs, const float* __restrict__ M_key,
    const float* __restrict__ M_value, const float* __restrict__ W_key,
    const float* __restrict__ W_value, float* __restrict__ out)
{
    __shared__ __align__(16) float h_s[UNITS];
    __shared__ float lg_s[MEM];
    __shared__ float at_s[MEM];
    __shared__ __align__(16) float red_s[2][UNITS];
    __shared__ __align__(16) float gpart[8][1024];   // 8 wave-partials, 32x32 each

    const int b    = blockIdx.x;
    const int tid  = threadIdx.x;
    const int wave = tid >> 6;
    const int lane = tid & 63;

    if (wave < 8) {
        // ================= fused path (512 threads) =================
        const size_t inrow = (size_t)b * LDA + EDIM;
        h_s[tid]       = inputs[inrow + tid];
        h_s[tid + 512] = inputs[inrow + tid + 512];
        __syncthreads();                                       // bar 1

        const float4 h0 = *(const float4*)(&h_s[lane * 4]);
        const float4 h1 = *(const float4*)(&h_s[lane * 4 + 256]);
        const float4 h2 = *(const float4*)(&h_s[lane * 4 + 512]);
        const float4 h3 = *(const float4*)(&h_s[lane * 4 + 768]);

        // ---- Phase A: stream M_key once: logits + shifted copy ----
        {
            const float* mrow0 = M_key + (size_t)b * (MEM * UNITS) + lane * 4;
            float*       drow0 = out + KEY_OFF + (size_t)b * (MEM * UNITS) + lane * 4;
            #pragma unroll 2
            for (int r = 0; r < 16; ++r) {
                const int m = wave * 16 + r;
                const float* mrow = mrow0 + (size_t)m * UNITS;
                float4 v0 = *(const float4*)(mrow);
                float4 v1 = *(const float4*)(mrow + 256);
                float4 v2 = *(const float4*)(mrow + 512);
                float4 v3 = *(const float4*)(mrow + 768);

                float acc = v0.x*h0.x + v0.y*h0.y + v0.z*h0.z + v0.w*h0.w
                          + v1.x*h1.x + v1.y*h1.y + v1.z*h1.z + v1.w*h1.w
                          + v2.x*h2.x + v2.y*h2.y + v2.z*h2.z + v2.w*h2.w
                          + v3.x*h3.x + v3.y*h3.y + v3.z*h3.z + v3.w*h3.w;
                #pragma unroll
                for (int off = 32; off > 0; off >>= 1)
                    acc += __shfl_xor(acc, off);
                if (lane == 0) lg_s[m] = acc;

                if (m > 0) {
                    float* drow = drow0 + (size_t)(m - 1) * UNITS;
                    nt_store4(drow,       v0);
                    nt_store4(drow + 256, v1);
                    nt_store4(drow + 512, v2);
                    nt_store4(drow + 768, v3);
                }
            }
        }
        __syncthreads();                                       // bar 2

        // ---- Phase B: softmax over 128 logits (wave 0) ----
        if (wave == 0) {
            float l0 = lg_s[lane], l1 = lg_s[lane + 64];
            float mx = fmaxf(l0, l1);
            #pragma unroll
            for (int off = 32; off > 0; off >>= 1)
                mx = fmaxf(mx, __shfl_xor(mx, off));
            float e0 = __expf(l0 - mx), e1 = __expf(l1 - mx);
            float s = e0 + e1;
            #pragma unroll
            for (int off = 32; off > 0; off >>= 1)
                s += __shfl_xor(s, off);
            float inv = 1.0f / s;
            at_s[lane]      = e0 * inv;
            at_s[lane + 64] = e1 * inv;
        }
        __syncthreads();                                       // bar 3

        // ---- Phase C: stream M_value once: weighted sum + shifted copy ----
        {
            const int rc  = wave >> 2;                 // 0/1 -> 64 rows each
            const int col = (wave & 3) * 256 + lane * 4;
            const float* vbase = M_value + (size_t)b * (MEM * UNITS) + col;
            float*       dbase = out + VAL_OFF + (size_t)b * (MEM * UNITS) + col;

            float4 acc = {0.f, 0.f, 0.f, 0.f};
            #pragma unroll 4
            for (int r = 0; r < 64; ++r) {
                const int m = rc * 64 + r;
                float4 v = *(const float4*)(vbase + (size_t)m * UNITS);
                const float w = at_s[m];
                acc.x += w * v.x; acc.y += w * v.y; acc.z += w * v.z; acc.w += w * v.w;
                if (m > 0)
                    nt_store4(dbase + (size_t)(m - 1) * UNITS, v);
            }
            *(float4*)(&red_s[rc][col]) = acc;
        }
        __syncthreads();                                       // bar 4

        if (wave < 4) {
            const int col = wave * 256 + lane * 4;
            float4 a0 = *(const float4*)(&red_s[0][col]);
            float4 a1 = *(const float4*)(&red_s[1][col]);
            float4 s = {a0.x + a1.x, a0.y + a1.y, a0.z + a1.z, a0.w + a1.w};
            *(float4*)(out + (size_t)b * UNITS + col) = s;
        }
    } else {
        // ================= GEMM path (waves 8-15) =================
        // 512 tiles of 32x32 over [2 W] x [256 rows] x [1024 cols]; 2 tiles per
        // block, 4 waves per tile (split-K=4, 256 k each), no LDS staging.
        const int gw = wave - 8;            // 0..7
        const int tl = gw >> 2;             // local tile 0/1
        const int kc = gw & 3;              // K chunk
        const int t  = b * 2 + tl;          // global tile 0..511
        const int w  = t >> 8;
        const int mt = (t & 255) >> 5;      // 0..7
        const int nt = t & 31;              // 0..31
        const int lr = lane >> 3;           // 0..7 (4 rows each)
        const int lc = lane & 7;            // 0..7 (4 cols each)
        const float* Wm = w ? W_value : W_key;

        const float* ap0 = inputs + (size_t)(mt * 32 + lr * 4) * LDA;
        const float* ap1 = ap0 + LDA;
        const float* ap2 = ap1 + LDA;
        const float* ap3 = ap2 + LDA;
        const float* bp  = Wm + nt * 32 + lc * 4;

        __syncthreads();                                       // bar 1

        float acc[4][4] = {};
        const int k0 = kc * 256;
        #pragma unroll 2
        for (int k = k0; k < k0 + 256; k += 4) {
            float4 a0 = *(const float4*)(ap0 + k);
            float4 a1 = *(const float4*)(ap1 + k);
            float4 a2 = *(const float4*)(ap2 + k);
            float4 a3 = *(const float4*)(ap3 + k);
            float4 b0 = *(const float4*)(bp + (size_t)(k + 0) * UNITS);
            float4 b1 = *(const float4*)(bp + (size_t)(k + 1) * UNITS);
            float4 b2 = *(const float4*)(bp + (size_t)(k + 2) * UNITS);
            float4 b3 = *(const float4*)(bp + (size_t)(k + 3) * UNITS);

            acc[0][0] += a0.x*b0.x + a0.y*b1.x + a0.z*b2.x + a0.w*b3.x;
            acc[0][1] += a0.x*b0.y + a0.y*b1.y + a0.z*b2.y + a0.w*b3.y;
            acc[0][2] += a0.x*b0.z + a0.y*b1.z + a0.z*b2.z + a0.w*b3.z;
            acc[0][3] += a0.x*b0.w + a0.y*b1.w + a0.z*b2.w + a0.w*b3.w;
            acc[1][0] += a1.x*b0.x + a1.y*b1.x + a1.z*b2.x + a1.w*b3.x;
            acc[1][1] += a1.x*b0.y + a1.y*b1.y + a1.z*b2.y + a1.w*b3.y;
            acc[1][2] += a1.x*b0.z + a1.y*b1.z + a1.z*b2.z + a1.w*b3.z;
            acc[1][3] += a1.x*b0.w + a1.y*b1.w + a1.z*b2.w + a1.w*b3.w;
            acc[2][0] += a2.x*b0.x + a2.y*b1.x + a2.z*b2.x + a2.w*b3.x;
            acc[2][1] += a2.x*b0.y + a2.y*b1.y + a2.z*b2.y + a2.w*b3.y;
            acc[2][2] += a2.x*b0.z + a2.y*b1.z + a2.z*b2.z + a2.w*b3.z;
            acc[2][3] += a2.x*b0.w + a2.y*b1.w + a2.z*b2.w + a2.w*b3.w;
            acc[3][0] += a3.x*b0.x + a3.y*b1.x + a3.z*b2.x + a3.w*b3.x;
            acc[3][1] += a3.x*b0.y + a3.y*b1.y + a3.z*b2.y + a3.w*b3.y;
            acc[3][2] += a3.x*b0.z + a3.y*b1.z + a3.z*b2.z + a3.w*b3.z;
            acc[3][3] += a3.x*b0.w + a3.y*b1.w + a3.z*b2.w + a3.w*b3.w;
        }

        #pragma unroll
        for (int i = 0; i < 4; ++i) {
            float4 v = {acc[i][0], acc[i][1], acc[i][2], acc[i][3]};
            *(float4*)(&gpart[gw][(lr * 4 + i) * 32 + lc * 4]) = v;
        }
        __syncthreads();                                       // bar 2

        // reduce split-K partials, scatter into row 127
        {
            const int idx = gw * 64 + lane;          // 0..511
            #pragma unroll
            for (int q = 0; q < 4; ++q) {
                const int o   = idx + q * 512;       // 0..2047
                const int tl2 = o >> 10;
                const int e   = o & 1023;
                float s = gpart[tl2 * 4 + 0][e] + gpart[tl2 * 4 + 1][e]
                        + gpart[tl2 * 4 + 2][e] + gpart[tl2 * 4 + 3][e];
                const int t2  = b * 2 + tl2;
                const int w2  = t2 >> 8;
                const int mt2 = (t2 & 255) >> 5;
                const int nt2 = t2 & 31;
                const int row = e >> 5, cin = e & 31;
                out[(w2 ? VAL_OFF : KEY_OFF)
                    + (size_t)(mt2 * 32 + row) * (MEM * UNITS)
                    + (size_t)(MEM - 1) * UNITS + nt2 * 32 + cin] = s;
            }
        }
        __syncthreads();                                       // bar 3
        __syncthreads();                                       // bar 4
    }
}

extern "C" void kernel_launch(void* const* d_in, const int* in_sizes, int n_in,
                              void* d_out, int out_size, void* d_ws, size_t ws_size,
                              hipStream_t stream)
{
    const float* inputs  = (const float*)d_in[0];
    const float* M_key   = (const float*)d_in[1];
    const float* M_value = (const float*)d_in[2];
    const float* W_key   = (const float*)d_in[3];
    const float* W_value = (const float*)d_in[4];
    float* out = (float*)d_out;

    hipLaunchKernelGGL(k_all, dim3(NB), dim3(1024), 0, stream,
                       inputs, M_key, M_value, W_key, W_value, out);
}

// Round 4
// 125.566 us; speedup vs baseline: 1.3088x; 1.3088x over previous
//
#include <hip/hip_runtime.h>

#define NB    256
#define UNITS 1024
#define EDIM  1024
#define MEM   128
#define LDA   2048   // inputs row stride (EDIM + UNITS)

// d_out layout (floats): output[256*1024] | new_M_key[256*128*1024] | new_M_value[256*128*1024]
#define KEY_OFF ((size_t)NB * UNITS)
#define VAL_OFF (KEY_OFF + (size_t)NB * MEM * UNITS)

// GEMM role: 128 blocks, one 64x64 output tile each (2 matrices x 4 Mtiles x 16 Ntiles).
// Per block: four 256-thread groups do split-K (256 k each) with LDS-staged
// 64x32 / 32x64 tiles, then an in-block LDS reduction writes row 127.
#define GROUP_F 4224              // floats per group region: As 32x68 + Bs 32x64
#define SMEM_FLOATS (4 * GROUP_F) // 67584 B

// One kernel, 384 blocks x 1024 threads.
//  blocks 0..255   : fused softmax-attention + memory shift (R1 structure, all 16
//                    waves streaming; HBM-bound)
//  blocks 256..383 : the two 256x1024x1024 fp32 GEMMs (row 127 of new_M_*),
//                    LDS-staged, in-block split-K. Co-resident with fused blocks
//                    (2 blocks/CU at VGPR<=64) -> GEMM hides under the stream.
__global__ __launch_bounds__(1024, 8) void k_all(
    const float* __restrict__ inputs, const float* __restrict__ M_key,
    const float* __restrict__ M_value, const float* __restrict__ W_key,
    const float* __restrict__ W_value, float* __restrict__ out)
{
    __shared__ __align__(16) float smem[SMEM_FLOATS];
    const int tid = threadIdx.x;

    if (blockIdx.x < NB) {
        // ========================= fused path =========================
        float* h_s  = smem;                                  // 1024
        float* lg_s = smem + 1024;                           // 128
        float* at_s = smem + 1152;                           // 128
        float (*red_s)[1024] = (float (*)[1024])(smem + 1280); // 4 x 1024

        const int b    = blockIdx.x;
        const int wave = tid >> 6;
        const int lane = tid & 63;

        h_s[tid] = inputs[(size_t)b * LDA + EDIM + tid];
        __syncthreads();

        const float4 h0 = *(const float4*)(&h_s[lane * 4]);
        const float4 h1 = *(const float4*)(&h_s[lane * 4 + 256]);
        const float4 h2 = *(const float4*)(&h_s[lane * 4 + 512]);
        const float4 h3 = *(const float4*)(&h_s[lane * 4 + 768]);

        // ---- Phase A: stream M_key once: logits + shifted copy ----
        {
            const float* mrow0 = M_key + (size_t)b * (MEM * UNITS) + lane * 4;
            float*       drow0 = out + KEY_OFF + (size_t)b * (MEM * UNITS) + lane * 4;
            #pragma unroll 2
            for (int r = 0; r < 8; ++r) {
                const int m = wave * 8 + r;
                const float* mrow = mrow0 + (size_t)m * UNITS;
                float4 v0 = *(const float4*)(mrow);
                float4 v1 = *(const float4*)(mrow + 256);
                float4 v2 = *(const float4*)(mrow + 512);
                float4 v3 = *(const float4*)(mrow + 768);

                float acc = v0.x*h0.x + v0.y*h0.y + v0.z*h0.z + v0.w*h0.w
                          + v1.x*h1.x + v1.y*h1.y + v1.z*h1.z + v1.w*h1.w
                          + v2.x*h2.x + v2.y*h2.y + v2.z*h2.z + v2.w*h2.w
                          + v3.x*h3.x + v3.y*h3.y + v3.z*h3.z + v3.w*h3.w;
                #pragma unroll
                for (int off = 32; off > 0; off >>= 1)
                    acc += __shfl_xor(acc, off);
                if (lane == 0) lg_s[m] = acc;

                if (m > 0) {
                    float* drow = drow0 + (size_t)(m - 1) * UNITS;
                    *(float4*)(drow)       = v0;
                    *(float4*)(drow + 256) = v1;
                    *(float4*)(drow + 512) = v2;
                    *(float4*)(drow + 768) = v3;
                }
            }
        }
        __syncthreads();

        // ---- Phase B: softmax over 128 logits (wave 0) ----
        if (wave == 0) {
            float l0 = lg_s[lane], l1 = lg_s[lane + 64];
            float mx = fmaxf(l0, l1);
            #pragma unroll
            for (int off = 32; off > 0; off >>= 1)
                mx = fmaxf(mx, __shfl_xor(mx, off));
            float e0 = __expf(l0 - mx), e1 = __expf(l1 - mx);
            float s = e0 + e1;
            #pragma unroll
            for (int off = 32; off > 0; off >>= 1)
                s += __shfl_xor(s, off);
            float inv = 1.0f / s;
            at_s[lane]      = e0 * inv;
            at_s[lane + 64] = e1 * inv;
        }
        __syncthreads();

        // ---- Phase C: stream M_value once: weighted sum + shifted copy ----
        {
            const int rc  = wave >> 2;                 // 0..3 -> 32 rows each
            const int col = (wave & 3) * 256 + lane * 4;
            const float* vbase = M_value + (size_t)b * (MEM * UNITS) + col;
            float*       dbase = out + VAL_OFF + (size_t)b * (MEM * UNITS) + col;

            float4 acc = {0.f, 0.f, 0.f, 0.f};
            #pragma unroll 4
            for (int r = 0; r < 32; ++r) {
                const int m = rc * 32 + r;
                float4 v = *(const float4*)(vbase + (size_t)m * UNITS);
                const float w = at_s[m];
                acc.x += w * v.x; acc.y += w * v.y; acc.z += w * v.z; acc.w += w * v.w;
                if (m > 0)
                    *(float4*)(dbase + (size_t)(m - 1) * UNITS) = v;
            }
            *(float4*)(&red_s[rc][col]) = acc;
        }
        __syncthreads();

        if (wave < 4) {
            const int col = wave * 256 + lane * 4;
            float4 a0 = *(const float4*)(&red_s[0][col]);
            float4 a1 = *(const float4*)(&red_s[1][col]);
            float4 a2 = *(const float4*)(&red_s[2][col]);
            float4 a3 = *(const float4*)(&red_s[3][col]);
            float4 s = {a0.x + a1.x + a2.x + a3.x,
                        a0.y + a1.y + a2.y + a3.y,
                        a0.z + a1.z + a2.z + a3.z,
                        a0.w + a1.w + a2.w + a3.w};
            *(float4*)(out + (size_t)b * UNITS + col) = s;
        }
    } else {
        // ========================= GEMM path =========================
        const int t  = blockIdx.x - NB;       // 0..127
        const int w  = t >> 6;                // which W matrix
        const int r  = t & 63;
        const int mt = r >> 4;                // 0..3  (64 rows)
        const int nt = r & 15;                // 0..15 (64 cols)
        const int kc   = tid >> 8;            // 0..3 (split-K group)
        const int gtid = tid & 255;
        const int ty = gtid >> 4, tx = gtid & 15;

        float* region = smem + kc * GROUP_F;
        float (*As)[68] = (float (*)[68])region;            // [k][m]
        float (*Bs)[64] = (float (*)[64])(region + 2176);   // [k][n]
        const float* Wm = w ? W_value : W_key;

        float acc[4][4] = {};
        const int k0 = kc * 256;

        for (int kt = k0; kt < k0 + 256; kt += 32) {
            #pragma unroll
            for (int q = 0; q < 2; ++q) {
                const int f  = gtid * 2 + q;          // 0..511
                const int ar = f >> 3;                // 0..63
                const int ac = (f & 7) << 2;          // 0..28
                float4 a = *(const float4*)(inputs + (size_t)(mt * 64 + ar) * LDA + kt + ac);
                As[ac + 0][ar] = a.x;
                As[ac + 1][ar] = a.y;
                As[ac + 2][ar] = a.z;
                As[ac + 3][ar] = a.w;
            }
            #pragma unroll
            for (int q = 0; q < 2; ++q) {
                const int f  = gtid * 2 + q;
                const int br = f >> 4;                // 0..31
                const int bc = (f & 15) << 2;         // 0..60
                *(float4*)(&Bs[br][bc]) =
                    *(const float4*)(Wm + (size_t)(kt + br) * UNITS + nt * 64 + bc);
            }
            __syncthreads();

            #pragma unroll
            for (int kk = 0; kk < 32; ++kk) {
                const float4 av = *(const float4*)(&As[kk][ty * 4]);
                const float4 bv = *(const float4*)(&Bs[kk][tx * 4]);
                acc[0][0] += av.x * bv.x; acc[0][1] += av.x * bv.y; acc[0][2] += av.x * bv.z; acc[0][3] += av.x * bv.w;
                acc[1][0] += av.y * bv.x; acc[1][1] += av.y * bv.y; acc[1][2] += av.y * bv.z; acc[1][3] += av.y * bv.w;
                acc[2][0] += av.z * bv.x; acc[2][1] += av.z * bv.y; acc[2][2] += av.z * bv.z; acc[2][3] += av.z * bv.w;
                acc[3][0] += av.w * bv.x; acc[3][1] += av.w * bv.y; acc[3][2] += av.w * bv.z; acc[3][3] += av.w * bv.w;
            }
            __syncthreads();
        }

        // each group writes its 64x64 partial over its own As/Bs region
        #pragma unroll
        for (int i = 0; i < 4; ++i) {
            float4 v = {acc[i][0], acc[i][1], acc[i][2], acc[i][3]};
            *(float4*)(region + (ty * 4 + i) * 64 + tx * 4) = v;
        }
        __syncthreads();

        // block-wide reduce of the 4 partials -> row 127 of new_M_{key,value}
        {
            const int e   = tid * 4;                  // 0..4092
            const int row = e >> 6;                   // 0..63
            const int col = e & 63;
            float4 p0 = *(const float4*)(smem + 0 * GROUP_F + e);
            float4 p1 = *(const float4*)(smem + 1 * GROUP_F + e);
            float4 p2 = *(const float4*)(smem + 2 * GROUP_F + e);
            float4 p3 = *(const float4*)(smem + 3 * GROUP_F + e);
            float4 s = {p0.x + p1.x + p2.x + p3.x,
                        p0.y + p1.y + p2.y + p3.y,
                        p0.z + p1.z + p2.z + p3.z,
                        p0.w + p1.w + p2.w + p3.w};
            *(float4*)(out + (w ? VAL_OFF : KEY_OFF)
                       + (size_t)(mt * 64 + row) * (MEM * UNITS)
                       + (size_t)(MEM - 1) * UNITS + nt * 64 + col) = s;
        }
    }
}

extern "C" void kernel_launch(void* const* d_in, const int* in_sizes, int n_in,
                              void* d_out, int out_size, void* d_ws, size_t ws_size,
                              hipStream_t stream)
{
    const float* inputs  = (const float*)d_in[0];
    const float* M_key   = (const float*)d_in[1];
    const float* M_value = (const float*)d_in[2];
    const float* W_key   = (const float*)d_in[3];
    const float* W_value = (const float*)d_in[4];
    float* out = (float*)d_out;

    hipLaunchKernelGGL(k_all, dim3(NB + 128), dim3(1024), 0, stream,
                       inputs, M_key, M_value, W_key, W_value, out);
}